// Round 4
// baseline (515.159 us; speedup 1.0000x reference)
//
#include <hip/hip_runtime.h>
#include <cstdint>

#define N_TOK 2048
#define CDIM  1024
#define NEXP  16
#define TOPK  2
#define HDIM  1024
#define SDIM  2048
#define ESLOT 48                     // max Sum_e ceil(cnt_e/128)
#define GU_EXP_BLOCKS (ESLOT * 16)   // 768 (16 n-tiles of 64 over HDIM)
#define GU_SH_BLOCKS  (16 * 32)      // 512 (16 m-tiles x 32 n-tiles over SDIM)
#define GU_NWG (GU_EXP_BLOCKS + GU_SH_BLOCKS)   // 1280 (div by 8)
#define DN_EXP_BLOCKS (ESLOT * 16)   // 768
#define DN_SH_BLOCKS  (16 * 16)      // 256
#define DN_NWG (DN_EXP_BLOCKS + DN_SH_BLOCKS)   // 1024 (div by 8)

typedef __bf16 bf16;
typedef __bf16 bf16x8 __attribute__((ext_vector_type(8)));
typedef float  f32x4  __attribute__((ext_vector_type(4)));
typedef unsigned int u32;
typedef unsigned short u16;

typedef __attribute__((address_space(3))) uint32_t lds_u32_t;
typedef __attribute__((address_space(1))) uint32_t glb_u32_t;

__device__ __forceinline__ void gload16(const void* g, void* l) {
  __builtin_amdgcn_global_load_lds((const glb_u32_t*)(uintptr_t)g,
                                   (lds_u32_t*)(uintptr_t)l, 16, 0, 0);
}
__device__ __forceinline__ float fromb(u16 s) {
  union { float f; u32 u; } z; z.u = ((u32)s) << 16; return z.f;
}
// chunked bijective XCD swizzle (nwg divisible by 8)
__device__ __forceinline__ int xcd_swz(int bid, int nwg) {
  return (bid & 7) * (nwg >> 3) + (bid >> 3);
}

// ---------------- router ----------------
__global__ void init_counts_kernel(int* counts) {
  if (threadIdx.x < NEXP) counts[threadIdx.x] = 0;
}

__global__ void router_kernel(const float* __restrict__ x,
                              const float* __restrict__ rw,
                              int* __restrict__ sel,
                              float* __restrict__ gatew,
                              int* __restrict__ counts) {
  int n = blockIdx.x;
  int lane = threadIdx.x;
  const float* xr = x + (size_t)n * CDIM;
  float acc[NEXP];
#pragma unroll
  for (int e = 0; e < NEXP; ++e) acc[e] = 0.f;
  for (int i = lane; i < CDIM; i += 64) {
    float xi = xr[i];
#pragma unroll
    for (int e = 0; e < NEXP; ++e) acc[e] += xi * rw[e * CDIM + i];
  }
#pragma unroll
  for (int off = 32; off > 0; off >>= 1) {
#pragma unroll
    for (int e = 0; e < NEXP; ++e) acc[e] += __shfl_xor(acc[e], off, 64);
  }
  if (lane == 0) {
    int i0 = 0; float v0 = acc[0];
#pragma unroll
    for (int e = 1; e < NEXP; ++e) if (acc[e] > v0) { v0 = acc[e]; i0 = e; }
    int i1 = (i0 == 0) ? 1 : 0; float v1 = acc[i1];
#pragma unroll
    for (int e = 0; e < NEXP; ++e) if (e != i0 && acc[e] > v1) { v1 = acc[e]; i1 = e; }
    sel[2 * n] = i0; sel[2 * n + 1] = i1;
    gatew[2 * n]     = 1.f / (1.f + expf(-v0));
    gatew[2 * n + 1] = 1.f / (1.f + expf(-v1));
    atomicAdd(&counts[i0], 1);
    atomicAdd(&counts[i1], 1);
  }
}

__global__ void scan_kernel(const int* __restrict__ counts,
                            int* __restrict__ offsets,
                            int* __restrict__ cursor,
                            int* __restrict__ tab128,
                            int* __restrict__ ntiles) {
  if (threadIdx.x == 0) {
    int s = 0, a = 0;
    for (int e = 0; e < NEXP; ++e) {
      offsets[e] = s; cursor[e] = s;
      int c = counts[e];
      for (int m0 = 0; m0 < c; m0 += 128) tab128[a++] = (e << 16) | m0;
      s += c;
    }
    ntiles[0] = a;
  }
}

__global__ void scatter_kernel(const int* __restrict__ sel,
                               const float* __restrict__ gatew,
                               int* __restrict__ cursor,
                               int* __restrict__ entry_token,
                               float* __restrict__ entry_gate,
                               int* __restrict__ entry_pos) {
  int t = blockIdx.x * blockDim.x + threadIdx.x;
  if (t >= N_TOK * TOPK) return;
  int e = sel[t];
  int pos = atomicAdd(&cursor[e], 1);
  entry_token[pos] = t >> 1;
  entry_gate[pos] = gatew[t];
  entry_pos[t] = pos;
}

// ---------------- x fp32 -> bf16 (once per call) ----------------
__global__ void convert_x_kernel(const float* __restrict__ x, bf16* __restrict__ xb) {
  int i = (blockIdx.x * 256 + threadIdx.x) * 8;
  float4 f0 = *(const float4*)(x + i);
  float4 f1 = *(const float4*)(x + i + 4);
  bf16x8 v;
  v[0]=(bf16)f0.x; v[1]=(bf16)f0.y; v[2]=(bf16)f0.z; v[3]=(bf16)f0.w;
  v[4]=(bf16)f1.x; v[5]=(bf16)f1.y; v[6]=(bf16)f1.z; v[7]=(bf16)f1.w;
  *(bf16x8*)(xb + i) = v;
}

// ---------------- pipelined gate+up GEMM (expert + shared in one launch) --------
// Tile 128m x 64n (dual-B: gate & up), BK=64, 4 waves each 64x32.
// A: bf16 via global_load_lds, LDS double-buffered. B: fp32 -> reg prefetch ->
// cvt+ds_write after compute barrier.
__global__ __launch_bounds__(256)
void gateup2(const bf16* __restrict__ xb,
             const float* __restrict__ guw,
             const float* __restrict__ sgw,
             const float* __restrict__ suw,
             bf16* __restrict__ h_exp,
             bf16* __restrict__ h_sh,
             const int* __restrict__ counts,
             const int* __restrict__ offsets,
             const int* __restrict__ entry_token,
             const int* __restrict__ tab128,
             const int* __restrict__ ntiles) {
  __shared__ __align__(16) bf16 sA[2][128 * 64];
  __shared__ __align__(16) bf16 sBg[64 * 64];
  __shared__ __align__(16) bf16 sBu[64 * 64];
  __shared__ int rowtok[128];

  const int bid = xcd_swz(blockIdx.x, GU_NWG);
  const int t = threadIdx.x;
  const bool is_exp = bid < GU_EXP_BLOCKS;
  const int wid = t >> 6, lane = t & 63;

  int n0, mguard;
  bf16* hbase; int hstride;
  const float *Bgp, *Bup;

  if (is_exp) {
    const int slot = bid >> 4;
    if (slot >= ntiles[0]) return;
    const int packed = tab128[slot];
    const int e = packed >> 16;
    const int m0 = packed & 0xffff;
    const int cnt = counts[e];
    const int base = offsets[e];
    n0 = (bid & 15) * 64;
    mguard = cnt - m0;
    if (t < 128) {
      int r = m0 + t;
      rowtok[t] = entry_token[base + ((r < cnt) ? r : (cnt - 1))];
    }
    Bgp = guw + (size_t)e * CDIM * 2 * HDIM + n0;   // k-major, ldb=2048
    Bup = Bgp + HDIM;
    hbase = h_exp + (size_t)(base + m0) * HDIM + n0;
    hstride = HDIM;
  } else {
    const int sid = bid - GU_EXP_BLOCKS;
    const int m0 = (sid >> 5) * 128;
    n0 = (sid & 31) * 64;
    mguard = 128;
    if (t < 128) rowtok[t] = m0 + t;
    Bgp = sgw + (size_t)n0 * CDIM;                  // n-major, ldb=1024
    Bup = suw + (size_t)n0 * CDIM;
    hbase = h_sh + (size_t)m0 * SDIM + n0;
    hstride = SDIM;
  }
  __syncthreads();

  // A-side global_load_lds setup (linear LDS dest + source-side chunk swizzle)
  const bf16* asrc[4];
  int adst[4];
#pragma unroll
  for (int i = 0; i < 4; ++i) {
    const int row_l = wid * 32 + i * 8 + (lane >> 3);
    const int c = (lane & 7) ^ (row_l & 7);
    asrc[i] = xb + (size_t)rowtok[row_l] * CDIM + c * 8;
    adst[i] = (wid * 32 + i * 8) * 64;
  }

  // B-side thread roles: t<128 gate, t>=128 up
  const int th = t & 127;
  const int kc = th >> 4, nb4 = (th & 15) * 4;      // expert path (k-major)
  const int brow = th >> 1, bhalf = th & 1;         // shared path (n-major)
  const float* bsrc;
  if (is_exp) bsrc = ((t >= 128) ? Bup : Bgp) + nb4;
  else        bsrc = ((t >= 128) ? Bup : Bgp) + (size_t)brow * CDIM + bhalf * 32;
  bf16* bdst = (t >= 128) ? sBu : sBg;

  float4 pf[8];
#define LOADB(k)                                                                \
  if (is_exp) {                                                                 \
    _Pragma("unroll")                                                           \
    for (int j = 0; j < 8; ++j)                                                 \
      pf[j] = *(const float4*)(bsrc + (size_t)((k) + kc * 8 + j) * (2 * HDIM)); \
  } else {                                                                      \
    _Pragma("unroll")                                                           \
    for (int j = 0; j < 8; ++j)                                                 \
      pf[j] = *(const float4*)(bsrc + (k) + j * 4);                             \
  }
#define CVTB()                                                                  \
  if (is_exp) {                                                                 \
    _Pragma("unroll")                                                           \
    for (int cc = 0; cc < 4; ++cc) {                                            \
      const int r = nb4 + cc; bf16x8 v;                                         \
      _Pragma("unroll")                                                         \
      for (int j = 0; j < 8; ++j) v[j] = (bf16)((&pf[j].x)[cc]);                \
      *(bf16x8*)&bdst[r * 64 + ((kc ^ (r & 7)) << 3)] = v;                      \
    }                                                                           \
  } else {                                                                      \
    _Pragma("unroll")                                                           \
    for (int q = 0; q < 4; ++q) {                                               \
      bf16x8 v;                                                                 \
      v[0]=(bf16)pf[2*q].x;   v[1]=(bf16)pf[2*q].y;                             \
      v[2]=(bf16)pf[2*q].z;   v[3]=(bf16)pf[2*q].w;                             \
      v[4]=(bf16)pf[2*q+1].x; v[5]=(bf16)pf[2*q+1].y;                           \
      v[6]=(bf16)pf[2*q+1].z; v[7]=(bf16)pf[2*q+1].w;                           \
      const int c = bhalf * 4 + q;                                              \
      *(bf16x8*)&bdst[brow * 64 + ((c ^ (brow & 7)) << 3)] = v;                 \
    }                                                                           \
  }

  const int wr = (wid >> 1) * 64, wc = (wid & 1) * 32;
  const int lrow = lane & 15, grp = lane >> 4;

  f32x4 ag[4][2], au[4][2];
#pragma unroll
  for (int m = 0; m < 4; ++m)
#pragma unroll
    for (int n = 0; n < 2; ++n)
#pragma unroll
      for (int i = 0; i < 4; ++i) { ag[m][n][i] = 0.f; au[m][n][i] = 0.f; }

  // prologue: stage tile 0
#pragma unroll
  for (int i = 0; i < 4; ++i) gload16(asrc[i], &sA[0][adst[i]]);
  LOADB(0)
  CVTB()
  __syncthreads();

  int cur = 0;
  for (int k0 = 0; k0 < CDIM; k0 += 64) {
    const int kn = (k0 + 64 < CDIM) ? k0 + 64 : CDIM - 64;
    // prefetch next tile (A -> LDS[cur^1] in flight, B -> regs in flight)
#pragma unroll
    for (int i = 0; i < 4; ++i) gload16(asrc[i] + kn, &sA[cur ^ 1][adst[i]]);
    LOADB(kn)
    // compute current tile
#pragma unroll
    for (int kk = 0; kk < 2; ++kk) {
      const int ch = kk * 4 + grp;
      bf16x8 av[4], bg[2], bu[2];
#pragma unroll
      for (int m = 0; m < 4; ++m) {
        const int r = wr + m * 16 + lrow;
        av[m] = *(const bf16x8*)&sA[cur][r * 64 + ((ch ^ (r & 7)) << 3)];
      }
#pragma unroll
      for (int n = 0; n < 2; ++n) {
        const int r = wc + n * 16 + lrow;
        bg[n] = *(const bf16x8*)&sBg[r * 64 + ((ch ^ (r & 7)) << 3)];
        bu[n] = *(const bf16x8*)&sBu[r * 64 + ((ch ^ (r & 7)) << 3)];
      }
#pragma unroll
      for (int m = 0; m < 4; ++m)
#pragma unroll
        for (int n = 0; n < 2; ++n) {
          ag[m][n] = __builtin_amdgcn_mfma_f32_16x16x32_bf16(av[m], bg[n], ag[m][n], 0, 0, 0);
          au[m][n] = __builtin_amdgcn_mfma_f32_16x16x32_bf16(av[m], bu[n], au[m][n], 0, 0, 0);
        }
    }
    __syncthreads();   // all waves done reading sB; pf/A-gload drained here
    CVTB()
    __syncthreads();   // sB(next) + sA[cur^1] ready
    cur ^= 1;
  }

  // SwiGLU epilogue (C/D: col=lane&15, row=grp*4+reg)
#pragma unroll
  for (int m = 0; m < 4; ++m) {
#pragma unroll
    for (int i = 0; i < 4; ++i) {
      const int rl = wr + m * 16 + grp * 4 + i;
      if (rl >= mguard) continue;
      bf16* orow = hbase + (size_t)rl * hstride;
#pragma unroll
      for (int n = 0; n < 2; ++n) {
        const float g = ag[m][n][i];
        const float u = au[m][n][i];
        orow[wc + n * 16 + lrow] = (bf16)(g * u * __builtin_amdgcn_rcpf(1.f + __expf(-g)));
      }
    }
  }
#undef LOADB
#undef CVTB
}

// ---------------- pipelined down GEMM (expert + shared in one launch) -----------
// Tile 128m x 64n, BK=64, 4 waves each 64x32. A bf16 (h) via gload_lds dbuf.
__global__ __launch_bounds__(256)
void down2(const bf16* __restrict__ h_exp,
           const bf16* __restrict__ h_sh,
           const float* __restrict__ dw,
           const float* __restrict__ sdw,
           const float* __restrict__ entry_gate,
           bf16* __restrict__ out_e,
           float* __restrict__ out,
           const int* __restrict__ counts,
           const int* __restrict__ offsets,
           const int* __restrict__ tab128,
           const int* __restrict__ ntiles) {
  __shared__ __align__(16) bf16 sA[2][128 * 64];
  __shared__ __align__(16) bf16 sB[64 * 64];

  const int bid = xcd_swz(blockIdx.x, DN_NWG);
  const int t = threadIdx.x;
  const bool is_exp = bid < DN_EXP_BLOCKS;
  const int wid = t >> 6, lane = t & 63;

  int n0, mguard, K, rowbase;
  const bf16* Ab;
  const float* bsrc0;

  if (is_exp) {
    const int slot = bid >> 4;
    if (slot >= ntiles[0]) return;
    const int packed = tab128[slot];
    const int e = packed >> 16;
    const int m0 = packed & 0xffff;
    const int cnt = counts[e];
    const int base = offsets[e];
    n0 = (bid & 15) * 64;
    mguard = cnt - m0;
    K = HDIM;
    rowbase = base + m0;
    Ab = h_exp;
    bsrc0 = dw + (size_t)e * HDIM * CDIM + n0;      // k-major, ldb=1024
  } else {
    const int sid = bid - DN_EXP_BLOCKS;
    const int m0 = (sid >> 4) * 128;
    n0 = (sid & 15) * 64;
    mguard = 128;
    K = SDIM;
    rowbase = m0;
    Ab = h_sh;
    bsrc0 = sdw;                                    // n-major, ldb=2048
  }

  const bf16* asrc[4];
  int adst[4];
#pragma unroll
  for (int i = 0; i < 4; ++i) {
    const int row_l = wid * 32 + i * 8 + (lane >> 3);
    const int c = (lane & 7) ^ (row_l & 7);
    int rg = rowbase + row_l;
    if (is_exp && rg > N_TOK * TOPK - 1) rg = N_TOK * TOPK - 1;
    asrc[i] = Ab + (size_t)rg * K + c * 8;
    adst[i] = (wid * 32 + i * 8) * 64;
  }

  const int th = t & 127;
  const int kc = th >> 4, nb4 = (th & 15) * 4;
  const int brow = th >> 1, bhalf = th & 1;
  const bool bactive = t < 128;
  const float* bsrc;
  if (is_exp) bsrc = bsrc0 + nb4;
  else        bsrc = bsrc0 + (size_t)(n0 + brow) * SDIM + bhalf * 32;

  float4 pf[8];
#define LOADB(k)                                                               \
  if (bactive) {                                                               \
    if (is_exp) {                                                              \
      _Pragma("unroll")                                                        \
      for (int j = 0; j < 8; ++j)                                              \
        pf[j] = *(const float4*)(bsrc + (size_t)((k) + kc * 8 + j) * CDIM);    \
    } else {                                                                   \
      _Pragma("unroll")                                                        \
      for (int j = 0; j < 8; ++j)                                              \
        pf[j] = *(const float4*)(bsrc + (k) + j * 4);                          \
    }                                                                          \
  }
#define CVTB()                                                                 \
  if (bactive) {                                                               \
    if (is_exp) {                                                              \
      _Pragma("unroll")                                                        \
      for (int cc = 0; cc < 4; ++cc) {                                         \
        const int r = nb4 + cc; bf16x8 v;                                      \
        _Pragma("unroll")                                                      \
        for (int j = 0; j < 8; ++j) v[j] = (bf16)((&pf[j].x)[cc]);             \
        *(bf16x8*)&sB[r * 64 + ((kc ^ (r & 7)) << 3)] = v;                     \
      }                                                                        \
    } else {                                                                   \
      _Pragma("unroll")                                                        \
      for (int q = 0; q < 4; ++q) {                                            \
        bf16x8 v;                                                              \
        v[0]=(bf16)pf[2*q].x;   v[1]=(bf16)pf[2*q].y;                          \
        v[2]=(bf16)pf[2*q].z;   v[3]=(bf16)pf[2*q].w;                          \
        v[4]=(bf16)pf[2*q+1].x; v[5]=(bf16)pf[2*q+1].y;                        \
        v[6]=(bf16)pf[2*q+1].z; v[7]=(bf16)pf[2*q+1].w;                        \
        const int c = bhalf * 4 + q;                                           \
        *(bf16x8*)&sB[brow * 64 + ((c ^ (brow & 7)) << 3)] = v;                \
      }                                                                        \
    }                                                                          \
  }

  const int wr = (wid >> 1) * 64, wc = (wid & 1) * 32;
  const int lrow = lane & 15, grp = lane >> 4;

  f32x4 acc[4][2];
#pragma unroll
  for (int m = 0; m < 4; ++m)
#pragma unroll
    for (int n = 0; n < 2; ++n)
#pragma unroll
      for (int i = 0; i < 4; ++i) acc[m][n][i] = 0.f;

#pragma unroll
  for (int i = 0; i < 4; ++i) gload16(asrc[i], &sA[0][adst[i]]);
  LOADB(0)
  CVTB()
  __syncthreads();

  int cur = 0;
  for (int k0 = 0; k0 < K; k0 += 64) {
    const int kn = (k0 + 64 < K) ? k0 + 64 : K - 64;
#pragma unroll
    for (int i = 0; i < 4; ++i) gload16(asrc[i] + kn, &sA[cur ^ 1][adst[i]]);
    LOADB(kn)
#pragma unroll
    for (int kk = 0; kk < 2; ++kk) {
      const int ch = kk * 4 + grp;
      bf16x8 av[4], bv[2];
#pragma unroll
      for (int m = 0; m < 4; ++m) {
        const int r = wr + m * 16 + lrow;
        av[m] = *(const bf16x8*)&sA[cur][r * 64 + ((ch ^ (r & 7)) << 3)];
      }
#pragma unroll
      for (int n = 0; n < 2; ++n) {
        const int r = wc + n * 16 + lrow;
        bv[n] = *(const bf16x8*)&sB[r * 64 + ((ch ^ (r & 7)) << 3)];
      }
#pragma unroll
      for (int m = 0; m < 4; ++m)
#pragma unroll
        for (int n = 0; n < 2; ++n)
          acc[m][n] = __builtin_amdgcn_mfma_f32_16x16x32_bf16(av[m], bv[n], acc[m][n], 0, 0, 0);
    }
    __syncthreads();
    CVTB()
    __syncthreads();
    cur ^= 1;
  }

#pragma unroll
  for (int m = 0; m < 4; ++m) {
#pragma unroll
    for (int i = 0; i < 4; ++i) {
      const int rl = wr + m * 16 + grp * 4 + i;
      if (rl >= mguard) continue;
      if (is_exp) {
        const int row = rowbase + rl;
        const float sc = entry_gate[row];
        bf16* orow = out_e + (size_t)row * CDIM + n0;
#pragma unroll
        for (int n = 0; n < 2; ++n)
          orow[wc + n * 16 + lrow] = (bf16)(acc[m][n][i] * sc);
      } else {
        float* orow = out + (size_t)(rowbase + rl) * CDIM + n0;
#pragma unroll
        for (int n = 0; n < 2; ++n)
          orow[wc + n * 16 + lrow] = acc[m][n][i];
      }
    }
  }
#undef LOADB
#undef CVTB
}

// ---------------- combine ----------------
__global__ void combine_kernel(float* __restrict__ out,
                               const bf16* __restrict__ out_e,
                               const int* __restrict__ entry_pos) {
  int tid = blockIdx.x * blockDim.x + threadIdx.x;
  int n = tid >> 8;
  int c4 = tid & 255;
  int p0 = entry_pos[2 * n];
  int p1 = entry_pos[2 * n + 1];
  float4 v = ((const float4*)out)[tid];
  ushort4 a = *(const ushort4*)((const u16*)out_e + (size_t)p0 * CDIM + c4 * 4);
  ushort4 b = *(const ushort4*)((const u16*)out_e + (size_t)p1 * CDIM + c4 * 4);
  v.x += fromb(a.x) + fromb(b.x);
  v.y += fromb(a.y) + fromb(b.y);
  v.z += fromb(a.z) + fromb(b.z);
  v.w += fromb(a.w) + fromb(b.w);
  ((float4*)out)[tid] = v;
}

extern "C" void kernel_launch(void* const* d_in, const int* in_sizes, int n_in,
                              void* d_out, int out_size, void* d_ws, size_t ws_size,
                              hipStream_t stream) {
  const float* x   = (const float*)d_in[0];
  const float* rw  = (const float*)d_in[1];
  const float* guw = (const float*)d_in[2];
  const float* dw  = (const float*)d_in[3];
  const float* sgw = (const float*)d_in[4];
  const float* suw = (const float*)d_in[5];
  const float* sdw = (const float*)d_in[6];
  float* out = (float*)d_out;
  char* ws = (char*)d_ws;

  int*   sel         = (int*)(ws + 0);
  float* gatew       = (float*)(ws + 16384);
  int*   counts      = (int*)(ws + 32768);
  int*   offsets     = (int*)(ws + 32832);
  int*   cursor      = (int*)(ws + 32896);
  int*   ntiles      = (int*)(ws + 32960);
  int*   tab128      = (int*)(ws + 33024);
  int*   entry_token = (int*)(ws + 33280);
  float* entry_gate  = (float*)(ws + 49664);
  int*   entry_pos   = (int*)(ws + 66048);
  bf16*  xb          = (bf16*)(ws + 82432);                         // 4 MB
  bf16*  h_exp       = (bf16*)(ws + 82432 + (size_t)4194304);       // 8 MB
  bf16*  h_sh        = (bf16*)(ws + 82432 + (size_t)12582912);      // 8 MB
  bf16*  out_e       = (bf16*)(ws + 82432 + (size_t)20971520);      // 8 MB

  convert_x_kernel<<<N_TOK * CDIM / 8 / 256, 256, 0, stream>>>(x, xb);
  init_counts_kernel<<<1, 64, 0, stream>>>(counts);
  router_kernel<<<N_TOK, 64, 0, stream>>>(x, rw, sel, gatew, counts);
  scan_kernel<<<1, 64, 0, stream>>>(counts, offsets, cursor, tab128, ntiles);
  scatter_kernel<<<16, 256, 0, stream>>>(sel, gatew, cursor, entry_token, entry_gate, entry_pos);

  gateup2<<<GU_NWG, 256, 0, stream>>>(xb, guw, sgw, suw, h_exp, h_sh,
                                      counts, offsets, entry_token, tab128, ntiles);

  down2<<<DN_NWG, 256, 0, stream>>>(h_exp, h_sh, dw, sdw, entry_gate, out_e, out,
                                    counts, offsets, tab128, ntiles);

  combine_kernel<<<(N_TOK * CDIM / 4) / 256, 256, 0, stream>>>(out, out_e, entry_pos);
}

// Round 5
// 276.594 us; speedup vs baseline: 1.8625x; 1.8625x over previous
//
#include <hip/hip_runtime.h>
#include <cstdint>

#define N_TOK 2048
#define CDIM  1024
#define NEXP  16
#define TOPK  2
#define HDIM  1024
#define SDIM  2048
#define ESLOT 48
#define GU_EXP_BLOCKS (ESLOT * 16)              // 768: 16 n-tiles of 64 h-cols
#define GU_SH_BLOCKS  (16 * 32)                 // 512: 16 m x 32 n(64) over SDIM
#define GU_NWG (GU_EXP_BLOCKS + GU_SH_BLOCKS)   // 1280
#define DN_EXP_BLOCKS (ESLOT * 8)               // 384: 8 n-tiles of 128
#define DN_SH_BLOCKS  (16 * 8)                  // 128
#define DN_NWG (DN_EXP_BLOCKS + DN_SH_BLOCKS)   // 512

typedef __bf16 bf16;
typedef __bf16 bf16x8 __attribute__((ext_vector_type(8)));
typedef float  f32x4  __attribute__((ext_vector_type(4)));
typedef unsigned int u32;
typedef unsigned short u16;

typedef __attribute__((address_space(3))) uint32_t lds_u32_t;
typedef __attribute__((address_space(1))) uint32_t glb_u32_t;

__device__ __forceinline__ void gload16(const void* g, void* l) {
  __builtin_amdgcn_global_load_lds((const glb_u32_t*)(uintptr_t)g,
                                   (lds_u32_t*)(uintptr_t)l, 16, 0, 0);
}
__device__ __forceinline__ float fromb(u16 s) {
  union { float f; u32 u; } z; z.u = ((u32)s) << 16; return z.f;
}
__device__ __forceinline__ int xcd_swz(int bid, int nwg) {
  return (bid & 7) * (nwg >> 3) + (bid >> 3);
}

// ---------------- router ----------------
__global__ void init_counts_kernel(int* counts) {
  if (threadIdx.x < NEXP) counts[threadIdx.x] = 0;
}

__global__ void router_kernel(const float* __restrict__ x,
                              const float* __restrict__ rw,
                              int* __restrict__ sel,
                              float* __restrict__ gatew,
                              int* __restrict__ counts) {
  int n = blockIdx.x;
  int lane = threadIdx.x;
  const float* xr = x + (size_t)n * CDIM;
  float acc[NEXP];
#pragma unroll
  for (int e = 0; e < NEXP; ++e) acc[e] = 0.f;
  for (int i = lane; i < CDIM; i += 64) {
    float xi = xr[i];
#pragma unroll
    for (int e = 0; e < NEXP; ++e) acc[e] += xi * rw[e * CDIM + i];
  }
#pragma unroll
  for (int off = 32; off > 0; off >>= 1) {
#pragma unroll
    for (int e = 0; e < NEXP; ++e) acc[e] += __shfl_xor(acc[e], off, 64);
  }
  if (lane == 0) {
    int i0 = 0; float v0 = acc[0];
#pragma unroll
    for (int e = 1; e < NEXP; ++e) if (acc[e] > v0) { v0 = acc[e]; i0 = e; }
    int i1 = (i0 == 0) ? 1 : 0; float v1 = acc[i1];
#pragma unroll
    for (int e = 0; e < NEXP; ++e) if (e != i0 && acc[e] > v1) { v1 = acc[e]; i1 = e; }
    sel[2 * n] = i0; sel[2 * n + 1] = i1;
    gatew[2 * n]     = 1.f / (1.f + expf(-v0));
    gatew[2 * n + 1] = 1.f / (1.f + expf(-v1));
    atomicAdd(&counts[i0], 1);
    atomicAdd(&counts[i1], 1);
  }
}

__global__ void scan_kernel(const int* __restrict__ counts,
                            int* __restrict__ offsets,
                            int* __restrict__ cursor,
                            int* __restrict__ tab128,
                            int* __restrict__ ntiles) {
  if (threadIdx.x == 0) {
    int s = 0, a = 0;
    for (int e = 0; e < NEXP; ++e) {
      offsets[e] = s; cursor[e] = s;
      int c = counts[e];
      for (int m0 = 0; m0 < c; m0 += 128) tab128[a++] = (e << 16) | m0;
      s += c;
    }
    ntiles[0] = a;
  }
}

__global__ void scatter_kernel(const int* __restrict__ sel,
                               const float* __restrict__ gatew,
                               int* __restrict__ cursor,
                               int* __restrict__ entry_token,
                               float* __restrict__ entry_gate,
                               int* __restrict__ entry_pos) {
  int t = blockIdx.x * blockDim.x + threadIdx.x;
  if (t >= N_TOK * TOPK) return;
  int e = sel[t];
  int pos = atomicAdd(&cursor[e], 1);
  entry_token[pos] = t >> 1;
  entry_gate[pos] = gatew[t];
  entry_pos[t] = pos;
}

__global__ void convert_x_kernel(const float* __restrict__ x, bf16* __restrict__ xb) {
  int i = (blockIdx.x * 256 + threadIdx.x) * 8;
  float4 f0 = *(const float4*)(x + i);
  float4 f1 = *(const float4*)(x + i + 4);
  bf16x8 v;
  v[0]=(bf16)f0.x; v[1]=(bf16)f0.y; v[2]=(bf16)f0.z; v[3]=(bf16)f0.w;
  v[4]=(bf16)f1.x; v[5]=(bf16)f1.y; v[6]=(bf16)f1.z; v[7]=(bf16)f1.w;
  *(bf16x8*)(xb + i) = v;
}

// ================= GU: gate+up GEMM, expert+shared, pipelined =================
// Tile 128m x 64h (dual-B), BK=64, 4 waves each 64m x 32h(gate+up).
// A: bf16 gload_lds dbuf. B: fp32 -> 8xf32x4 reg prefetch -> cvt+ds_write.
__global__ __launch_bounds__(256, 3)
void gu3(const bf16* __restrict__ xb,
         const float* __restrict__ guw,
         const float* __restrict__ sgw,
         const float* __restrict__ suw,
         bf16* __restrict__ h_exp,
         bf16* __restrict__ h_sh,
         const int* __restrict__ counts,
         const int* __restrict__ offsets,
         const int* __restrict__ entry_token,
         const int* __restrict__ tab128,
         const int* __restrict__ ntiles) {
  __shared__ __align__(16) bf16 sA[2][128 * 64];
  __shared__ __align__(16) bf16 sBg[64 * 64];
  __shared__ __align__(16) bf16 sBu[64 * 64];
  __shared__ int rowtok[128];

  const int bid = xcd_swz(blockIdx.x, GU_NWG);
  const int t = threadIdx.x;
  const bool is_exp = bid < GU_EXP_BLOCKS;
  const int wid = t >> 6, lane = t & 63;

  int n0, mguard;
  bf16* hbase; int hstride;
  const float *Bgp, *Bup; int ldb;

  if (is_exp) {
    const int slot = bid >> 4;
    if (slot >= ntiles[0]) return;
    const int packed = tab128[slot];
    const int e = packed >> 16;
    const int m0 = packed & 0xffff;
    const int cnt = counts[e];
    const int base = offsets[e];
    n0 = (bid & 15) * 64;
    mguard = cnt - m0;
    if (t < 128) {
      int r = m0 + t;
      rowtok[t] = entry_token[base + ((r < cnt) ? r : (cnt - 1))];
    }
    Bgp = guw + (size_t)e * CDIM * 2 * HDIM + n0;          // k-major
    Bup = Bgp + HDIM;
    ldb = 2 * HDIM;
    hbase = h_exp + (size_t)(base + m0) * HDIM + n0;
    hstride = HDIM;
  } else {
    const int sid = bid - GU_EXP_BLOCKS;
    const int m0 = (sid >> 5) * 128;
    n0 = (sid & 31) * 64;
    mguard = 128;
    if (t < 128) rowtok[t] = m0 + t;
    Bgp = sgw + (size_t)n0 * CDIM;                         // n-major
    Bup = suw + (size_t)n0 * CDIM;
    ldb = CDIM;
    hbase = h_sh + (size_t)m0 * SDIM + n0;
    hstride = SDIM;
  }
  __syncthreads();

  // A staging: 4 gload16/thread, 128 rows x 64k bf16, linear dest, src chunk-swz
  const bf16* asrc[4];
#pragma unroll
  for (int i = 0; i < 4; ++i) {
    const int row = i * 32 + (t >> 3);
    const int c = (t & 7) ^ (row & 7);
    asrc[i] = xb + (size_t)rowtok[row] * CDIM + c * 8;
  }
  const int adst = t * 8;   // bf16 units; +i*2048

  // B staging roles: t<128 gate, t>=128 up
  const int th = t & 127;
  bf16* bdst = (t >= 128) ? sBu : sBg;
  const float* Bp = (t >= 128) ? Bup : Bgp;
  // expert (k-major): k = (th>>4)*8+j, col4 = (th&15)*4
  const int ek = th >> 4, ec4 = (th & 15) * 4;
  // shared (n-major): row = th>>1, half = th&1
  const int srow = th >> 1, shalf = th & 1;

  f32x4 pf[8];

#define LOADB(k0_)                                                            \
  if (is_exp) {                                                               \
    _Pragma("unroll")                                                         \
    for (int j = 0; j < 8; ++j)                                               \
      pf[j] = *(const f32x4*)(Bp + (size_t)((k0_) + ek * 8 + j) * ldb + ec4); \
  } else {                                                                    \
    _Pragma("unroll")                                                         \
    for (int j = 0; j < 8; ++j)                                               \
      pf[j] = *(const f32x4*)(Bp + (size_t)srow * CDIM + (k0_) + shalf * 32 + j * 4); \
  }

#define CVTB()                                                                \
  if (is_exp) {                                                               \
    _Pragma("unroll")                                                         \
    for (int n = 0; n < 4; ++n) {                                             \
      const int rb = ec4 + n; bf16x8 v;                                       \
      _Pragma("unroll")                                                       \
      for (int j = 0; j < 8; ++j) v[j] = (bf16)pf[j][n];                      \
      *(bf16x8*)&bdst[rb * 64 + ((ek ^ (rb & 7)) << 3)] = v;                  \
    }                                                                         \
  } else {                                                                    \
    _Pragma("unroll")                                                         \
    for (int q = 0; q < 4; ++q) {                                             \
      bf16x8 v;                                                               \
      v[0]=(bf16)pf[2*q][0]; v[1]=(bf16)pf[2*q][1];                           \
      v[2]=(bf16)pf[2*q][2]; v[3]=(bf16)pf[2*q][3];                           \
      v[4]=(bf16)pf[2*q+1][0]; v[5]=(bf16)pf[2*q+1][1];                       \
      v[6]=(bf16)pf[2*q+1][2]; v[7]=(bf16)pf[2*q+1][3];                       \
      const int c = shalf * 4 + q;                                            \
      *(bf16x8*)&bdst[srow * 64 + ((c ^ (srow & 7)) << 3)] = v;               \
    }                                                                         \
  }

  const int wr = (wid >> 1) * 64, wc = (wid & 1) * 32;
  const int lrow = lane & 15, grp = lane >> 4;

  f32x4 ag[4][2], au[4][2];
#pragma unroll
  for (int m = 0; m < 4; ++m)
#pragma unroll
    for (int n = 0; n < 2; ++n)
#pragma unroll
      for (int i = 0; i < 4; ++i) { ag[m][n][i] = 0.f; au[m][n][i] = 0.f; }

  // prologue
#pragma unroll
  for (int i = 0; i < 4; ++i) gload16(asrc[i], &sA[0][adst + i * 2048]);
  LOADB(0)
  CVTB()
  __syncthreads();

  int p = 0;
  for (int k0 = 0; k0 < CDIM; k0 += 64) {
    const int kn = (k0 + 64 < CDIM) ? k0 + 64 : 0;   // wrap-safe dummy
    if (k0 + 64 < CDIM) {
#pragma unroll
      for (int i = 0; i < 4; ++i) gload16(asrc[i] + kn, &sA[p ^ 1][adst + i * 2048]);
      LOADB(kn)
    }
#pragma unroll
    for (int ks = 0; ks < 2; ++ks) {
      const int ch = ks * 4 + grp;
      bf16x8 av[4], bg[2], bu[2];
#pragma unroll
      for (int m = 0; m < 4; ++m) {
        const int r = wr + m * 16 + lrow;
        av[m] = *(const bf16x8*)&sA[p][r * 64 + ((ch ^ (r & 7)) << 3)];
      }
#pragma unroll
      for (int n = 0; n < 2; ++n) {
        const int r = wc + n * 16 + lrow;
        bg[n] = *(const bf16x8*)&sBg[r * 64 + ((ch ^ (r & 7)) << 3)];
        bu[n] = *(const bf16x8*)&sBu[r * 64 + ((ch ^ (r & 7)) << 3)];
      }
#pragma unroll
      for (int m = 0; m < 4; ++m)
#pragma unroll
        for (int n = 0; n < 2; ++n) {
          ag[m][n] = __builtin_amdgcn_mfma_f32_16x16x32_bf16(av[m], bg[n], ag[m][n], 0, 0, 0);
          au[m][n] = __builtin_amdgcn_mfma_f32_16x16x32_bf16(av[m], bu[n], au[m][n], 0, 0, 0);
        }
    }
    __syncthreads();      // waves done reading sB; gloads+pf drained
    if (k0 + 64 < CDIM) {
      CVTB()
      __syncthreads();    // next sB and sA[p^1] ready
      p ^= 1;
    }
  }

  // SwiGLU epilogue (C/D: col=lane&15, row=grp*4+i)
#pragma unroll
  for (int m = 0; m < 4; ++m) {
#pragma unroll
    for (int i = 0; i < 4; ++i) {
      const int rl = wr + m * 16 + grp * 4 + i;
      if (rl >= mguard) continue;
      bf16* orow = hbase + (size_t)rl * hstride;
#pragma unroll
      for (int n = 0; n < 2; ++n) {
        const float g = ag[m][n][i];
        const float u = au[m][n][i];
        orow[wc + n * 16 + lrow] = (bf16)(g * u * __builtin_amdgcn_rcpf(1.f + __expf(-g)));
      }
    }
  }
#undef LOADB
#undef CVTB
}

// ================= DOWN GEMM, expert+shared, pipelined =================
// Tile 128m x 128n, BK=64, 4 waves each 64x64.
__global__ __launch_bounds__(256, 3)
void dn3(const bf16* __restrict__ h_exp,
         const bf16* __restrict__ h_sh,
         const float* __restrict__ dw,
         const float* __restrict__ sdw,
         const float* __restrict__ entry_gate,
         bf16* __restrict__ out_e,
         float* __restrict__ out,
         const int* __restrict__ counts,
         const int* __restrict__ offsets,
         const int* __restrict__ tab128,
         const int* __restrict__ ntiles) {
  __shared__ __align__(16) bf16 sA[2][128 * 64];
  __shared__ __align__(16) bf16 sB[128 * 64];

  const int bid = xcd_swz(blockIdx.x, DN_NWG);
  const int t = threadIdx.x;
  const bool is_exp = bid < DN_EXP_BLOCKS;
  const int wid = t >> 6, lane = t & 63;

  int n0, mguard, K, rowbase;
  const bf16* Ab;
  const float* Bp;

  if (is_exp) {
    const int slot = bid >> 3;
    if (slot >= ntiles[0]) return;
    const int packed = tab128[slot];
    const int e = packed >> 16;
    const int m0 = packed & 0xffff;
    const int cnt = counts[e];
    n0 = (bid & 7) * 128;
    mguard = cnt - m0;
    K = HDIM;
    rowbase = offsets[e] + m0;
    Ab = h_exp;
    Bp = dw + (size_t)e * HDIM * CDIM + n0;    // k-major, ldb=1024
  } else {
    const int sid = bid - DN_EXP_BLOCKS;
    const int m0 = (sid >> 3) * 128;
    n0 = (sid & 7) * 128;
    mguard = 128;
    K = SDIM;
    rowbase = m0;
    Ab = h_sh;
    Bp = sdw;                                   // n-major, ldb=2048
  }

  const bf16* asrc[4];
#pragma unroll
  for (int i = 0; i < 4; ++i) {
    const int row = i * 32 + (t >> 3);
    const int c = (t & 7) ^ (row & 7);
    int rg = rowbase + row;
    if (is_exp && rg > N_TOK * TOPK - 1) rg = N_TOK * TOPK - 1;
    asrc[i] = Ab + (size_t)rg * K + c * 8;
  }
  const int adst = t * 8;

  // expert (k-major dw): k = (t>>5)*8+j, col4 = (t&31)*4 (512B segments)
  const int ek = t >> 5, ec4 = (t & 31) * 4;
  // shared (n-major sdw): row = t>>1, half = t&1
  const int srow = t >> 1, shalf = t & 1;

  f32x4 pf[8];

#define LOADB(k0_)                                                             \
  if (is_exp) {                                                                \
    _Pragma("unroll")                                                          \
    for (int j = 0; j < 8; ++j)                                                \
      pf[j] = *(const f32x4*)(Bp + (size_t)((k0_) + ek * 8 + j) * CDIM + ec4); \
  } else {                                                                     \
    _Pragma("unroll")                                                          \
    for (int j = 0; j < 8; ++j)                                                \
      pf[j] = *(const f32x4*)(Bp + (size_t)(n0 + srow) * SDIM + (k0_) + shalf * 32 + j * 4); \
  }

#define CVTB()                                                                 \
  if (is_exp) {                                                                \
    _Pragma("unroll")                                                         \
    for (int n = 0; n < 4; ++n) {                                              \
      const int rb = ec4 + n; bf16x8 v;                                        \
      _Pragma("unroll")                                                        \
      for (int j = 0; j < 8; ++j) v[j] = (bf16)pf[j][n];                       \
      *(bf16x8*)&sB[rb * 64 + ((ek ^ (rb & 7)) << 3)] = v;                     \
    }                                                                          \
  } else {                                                                     \
    _Pragma("unroll")                                                          \
    for (int q = 0; q < 4; ++q) {                                              \
      bf16x8 v;                                                                \
      v[0]=(bf16)pf[2*q][0]; v[1]=(bf16)pf[2*q][1];                            \
      v[2]=(bf16)pf[2*q][2]; v[3]=(bf16)pf[2*q][3];                            \
      v[4]=(bf16)pf[2*q+1][0]; v[5]=(bf16)pf[2*q+1][1];                        \
      v[6]=(bf16)pf[2*q+1][2]; v[7]=(bf16)pf[2*q+1][3];                        \
      const int c = shalf * 4 + q;                                             \
      *(bf16x8*)&sB[srow * 64 + ((c ^ (srow & 7)) << 3)] = v;                  \
    }                                                                          \
  }

  const int wr = (wid >> 1) * 64, wc = (wid & 1) * 64;
  const int lrow = lane & 15, grp = lane >> 4;

  f32x4 acc[4][4];
#pragma unroll
  for (int m = 0; m < 4; ++m)
#pragma unroll
    for (int n = 0; n < 4; ++n)
#pragma unroll
      for (int i = 0; i < 4; ++i) acc[m][n][i] = 0.f;

#pragma unroll
  for (int i = 0; i < 4; ++i) gload16(asrc[i], &sA[0][adst + i * 2048]);
  LOADB(0)
  CVTB()
  __syncthreads();

  int p = 0;
  for (int k0 = 0; k0 < K; k0 += 64) {
    const int kn = k0 + 64;
    if (kn < K) {
#pragma unroll
      for (int i = 0; i < 4; ++i) gload16(asrc[i] + kn, &sA[p ^ 1][adst + i * 2048]);
      LOADB(kn)
    }
#pragma unroll
    for (int ks = 0; ks < 2; ++ks) {
      const int ch = ks * 4 + grp;
      bf16x8 av[4], bv[4];
#pragma unroll
      for (int m = 0; m < 4; ++m) {
        const int r = wr + m * 16 + lrow;
        av[m] = *(const bf16x8*)&sA[p][r * 64 + ((ch ^ (r & 7)) << 3)];
      }
#pragma unroll
      for (int n = 0; n < 4; ++n) {
        const int r = wc + n * 16 + lrow;
        bv[n] = *(const bf16x8*)&sB[r * 64 + ((ch ^ (r & 7)) << 3)];
      }
#pragma unroll
      for (int m = 0; m < 4; ++m)
#pragma unroll
        for (int n = 0; n < 4; ++n)
          acc[m][n] = __builtin_amdgcn_mfma_f32_16x16x32_bf16(av[m], bv[n], acc[m][n], 0, 0, 0);
    }
    __syncthreads();
    if (kn < K) {
      CVTB()
      __syncthreads();
      p ^= 1;
    }
  }

#pragma unroll
  for (int m = 0; m < 4; ++m) {
#pragma unroll
    for (int i = 0; i < 4; ++i) {
      const int rl = wr + m * 16 + grp * 4 + i;
      if (rl >= mguard) continue;
      if (is_exp) {
        const int row = rowbase + rl;
        const float sc = entry_gate[row];
        bf16* orow = out_e + (size_t)row * CDIM + n0;
#pragma unroll
        for (int n = 0; n < 4; ++n)
          orow[wc + n * 16 + lrow] = (bf16)(acc[m][n][i] * sc);
      } else {
        float* orow = out + (size_t)(rowbase + rl) * CDIM + n0;
#pragma unroll
        for (int n = 0; n < 4; ++n)
          orow[wc + n * 16 + lrow] = acc[m][n][i];
      }
    }
  }
#undef LOADB
#undef CVTB
}

// ---------------- combine ----------------
__global__ void combine_kernel(float* __restrict__ out,
                               const bf16* __restrict__ out_e,
                               const int* __restrict__ entry_pos) {
  int tid = blockIdx.x * blockDim.x + threadIdx.x;
  int n = tid >> 8;
  int c4 = tid & 255;
  int p0 = entry_pos[2 * n];
  int p1 = entry_pos[2 * n + 1];
  float4 v = ((const float4*)out)[tid];
  ushort4 a = *(const ushort4*)((const u16*)out_e + (size_t)p0 * CDIM + c4 * 4);
  ushort4 b = *(const ushort4*)((const u16*)out_e + (size_t)p1 * CDIM + c4 * 4);
  v.x += fromb(a.x) + fromb(b.x);
  v.y += fromb(a.y) + fromb(b.y);
  v.z += fromb(a.z) + fromb(b.z);
  v.w += fromb(a.w) + fromb(b.w);
  ((float4*)out)[tid] = v;
}

extern "C" void kernel_launch(void* const* d_in, const int* in_sizes, int n_in,
                              void* d_out, int out_size, void* d_ws, size_t ws_size,
                              hipStream_t stream) {
  const float* x   = (const float*)d_in[0];
  const float* rw  = (const float*)d_in[1];
  const float* guw = (const float*)d_in[2];
  const float* dw  = (const float*)d_in[3];
  const float* sgw = (const float*)d_in[4];
  const float* suw = (const float*)d_in[5];
  const float* sdw = (const float*)d_in[6];
  float* out = (float*)d_out;
  char* ws = (char*)d_ws;

  int*   sel         = (int*)(ws + 0);
  float* gatew       = (float*)(ws + 16384);
  int*   counts      = (int*)(ws + 32768);
  int*   offsets     = (int*)(ws + 32832);
  int*   cursor      = (int*)(ws + 32896);
  int*   ntiles      = (int*)(ws + 32960);
  int*   tab128      = (int*)(ws + 33024);
  int*   entry_token = (int*)(ws + 33280);
  float* entry_gate  = (float*)(ws + 49664);
  int*   entry_pos   = (int*)(ws + 66048);
  bf16*  xb          = (bf16*)(ws + 82432);                       // 4 MB
  bf16*  h_exp       = (bf16*)(ws + 82432 + (size_t)4194304);     // 8 MB
  bf16*  h_sh        = (bf16*)(ws + 82432 + (size_t)12582912);    // 8 MB
  bf16*  out_e       = (bf16*)(ws + 82432 + (size_t)20971520);    // 8 MB

  convert_x_kernel<<<N_TOK * CDIM / 8 / 256, 256, 0, stream>>>(x, xb);
  init_counts_kernel<<<1, 64, 0, stream>>>(counts);
  router_kernel<<<N_TOK, 64, 0, stream>>>(x, rw, sel, gatew, counts);
  scan_kernel<<<1, 64, 0, stream>>>(counts, offsets, cursor, tab128, ntiles);
  scatter_kernel<<<16, 256, 0, stream>>>(sel, gatew, cursor, entry_token, entry_gate, entry_pos);

  gu3<<<GU_NWG, 256, 0, stream>>>(xb, guw, sgw, suw, h_exp, h_sh,
                                  counts, offsets, entry_token, tab128, ntiles);

  dn3<<<DN_NWG, 256, 0, stream>>>(h_exp, h_sh, dw, sdw, entry_gate, out_e, out,
                                  counts, offsets, tab128, ntiles);

  combine_kernel<<<(N_TOK * CDIM / 4) / 256, 256, 0, stream>>>(out, out_e, entry_pos);
}